// Round 9
// baseline (2285.179 us; speedup 1.0000x reference)
//
#include <hip/hip_runtime.h>

#define I_SZ 256
#define H_SZ 512
#define O_SZ 256
#define B_SZ 4096
#define S_SZ 50
#define T_SZ 20
#define G4H  2048
#define BH   ((size_t)B_SZ * H_SZ)
#define NB   512                 // persistent grid: 2 blocks/CU x 256 CUs

#define PAD 72    // k_fc only
#define PAD_H 36  // epilogue h repack stride (halves)

typedef _Float16 half8 __attribute__((ext_vector_type(8)));
typedef float f32x4 __attribute__((ext_vector_type(4)));

template<int N> struct IC { static constexpr int value = N; };

__device__ __forceinline__ float sigm(float x) {
    return 1.0f / (1.0f + __expf(-x));
}
__device__ __forceinline__ float tanh_fast(float x) {
    float e = __expf(2.0f * x);
    return 1.0f - 2.0f / (e + 1.0f);
}

// async global->LDS, 16B/lane, linear LDS dest, cached (L1+L2)
#define GLDS(gp, lp) __builtin_amdgcn_global_load_lds(                      \
    (const __attribute__((address_space(1))) void*)(gp),                    \
    (__attribute__((address_space(3))) void*)(lp), 16, 0, 0)

#define MEMFENCE asm volatile("" ::: "memory")

// ---------------- one-time prep kernels ----------------
__global__ void k_zeroN(unsigned* p, int n) {
    int i = blockIdx.x * blockDim.x + threadIdx.x;
    if (i < n) p[i] = 0u;
}

__global__ void k_cvt(const float* __restrict__ src, _Float16* __restrict__ dst, int n) {
    int i = blockIdx.x * blockDim.x + threadIdx.x;
    if (i < n) dst[i] = (_Float16)src[i];
}

__global__ void k_bias_combine(const float* __restrict__ a, const float* __restrict__ b,
                               float* __restrict__ dst, int n) {
    int i = blockIdx.x * blockDim.x + threadIdx.x;
    if (i < n) dst[i] = a[i] + b[i];
}

// x [B][S][I] fp32 -> xT [S][B][I] fp16
__global__ __launch_bounds__(256) void k_cvt_x(const float* __restrict__ x,
                                               _Float16* __restrict__ xT) {
    size_t idx = ((size_t)blockIdx.x * 256 + threadIdx.x) * 8;
    int i = (int)(idx & 255);
    int s = (int)((idx >> 8) % S_SZ);
    size_t b = idx / (256 * S_SZ);
    float4 v0 = *(const float4*)(x + idx);
    float4 v1 = *(const float4*)(x + idx + 4);
    half8 hv;
    hv[0] = (_Float16)v0.x; hv[1] = (_Float16)v0.y;
    hv[2] = (_Float16)v0.z; hv[3] = (_Float16)v0.w;
    hv[4] = (_Float16)v1.x; hv[5] = (_Float16)v1.y;
    hv[6] = (_Float16)v1.z; hv[7] = (_Float16)v1.w;
    *(half8*)(xT + (((size_t)s * B_SZ + b) * I_SZ + i)) = hv;
}

// Wenc[r][0:256]=eWih[r], [256:768]=eWhh[r]  (fp16)
__global__ void k_wenc(const float* __restrict__ eWih, const float* __restrict__ eWhh,
                       _Float16* __restrict__ Wenc) {
    int idx = blockIdx.x * blockDim.x + threadIdx.x;
    int r = idx / 768, col = idx % 768;
    float v = (col < 256) ? eWih[(size_t)r * 256 + col] : eWhh[(size_t)r * 512 + col - 256];
    Wenc[idx] = (_Float16)v;
}

// Wd[r,k] = dWhh[r,k] + sum_o dWih[r,o] * fcW[o,k]
__global__ __launch_bounds__(256) void k_wd(
    const float* __restrict__ dWhh, const float* __restrict__ dWih,
    const float* __restrict__ fcW, _Float16* __restrict__ Wd)
{
    __shared__ float sA[8][256];
    const int tid = threadIdx.x;
    const int r0 = blockIdx.x * 8;
    {
        int linear = tid * 8;
        int row = linear >> 8, col = linear & 255;
        const float4* p = (const float4*)(dWih + (size_t)(r0 + row) * 256 + col);
        float4 v0 = p[0], v1 = p[1];
        *(float4*)&sA[row][col]     = v0;
        *(float4*)&sA[row][col + 4] = v1;
    }
    __syncthreads();
    float acc[8][2] = {};
    const int k = tid;
    for (int i = 0; i < 256; ++i) {
        float w0 = fcW[(size_t)i * 512 + k];
        float w1 = fcW[(size_t)i * 512 + k + 256];
        #pragma unroll
        for (int rr = 0; rr < 8; ++rr) {
            float a = sA[rr][i];
            acc[rr][0] += a * w0;
            acc[rr][1] += a * w1;
        }
    }
    #pragma unroll
    for (int rr = 0; rr < 8; ++rr) {
        size_t base = (size_t)(r0 + rr) * 512;
        Wd[base + k]       = (_Float16)(dWhh[base + k]       + acc[rr][0]);
        Wd[base + k + 256] = (_Float16)(dWhh[base + k + 256] + acc[rr][1]);
    }
}

// bd[r] = db[r] + sum_o dWih[r,o] * fcb[o]
__global__ __launch_bounds__(256) void k_bd(
    const float* __restrict__ dWih, const float* __restrict__ fcb,
    const float* __restrict__ db, float* __restrict__ bd)
{
    __shared__ float sf[256];
    const int tid = threadIdx.x;
    sf[tid] = fcb[tid];
    __syncthreads();
    int r = blockIdx.x * 256 + tid;
    float acc = db[r];
    const float* row = dWih + (size_t)r * 256;
    for (int o = 0; o < 256; o += 4) {
        float4 v = *(const float4*)(row + o);
        acc += v.x * sf[o] + v.y * sf[o + 1] + v.z * sf[o + 2] + v.w * sf[o + 3];
    }
    bd[r] = acc;
}

// ---------------- persistent whole-recurrence kernel ----------------
// A (x|h) direct global->register, 1-ahead, compiler-tracked. B (weights) via
// global_load_lds into 4 LDS buffers, 2-ahead, counted vmcnt, ONE barrier/iter.
// Unique h slab per step (fresh addresses -> plain cached reads are coherent);
// producers use sc write-through stores + relaxed group counters.
__global__ __launch_bounds__(256, 2) void k_lstm_all(
    const _Float16* __restrict__ xT,     // [S][B][256] fp16
    const _Float16* __restrict__ Wenc,   // [2048][768]
    const _Float16* __restrict__ dWhh_h, // [2048][512]
    const _Float16* __restrict__ Wd,     // [2048][512]
    const float* __restrict__ eb, const float* __restrict__ db,
    const float* __restrict__ bd,
    _Float16* __restrict__ henc,         // [49][B][512] unique slabs
    _Float16* __restrict__ hseq,         // [21][B][512]
    unsigned* __restrict__ bar)          // 32 counters, 16 uints apart
{
    __shared__ _Float16 Bs[4][8192];     // 4 x 16KB B buffers (hsm aliases Bs[2])

    const int tid = threadIdx.x;
    const int xcd = blockIdx.x & 7, slot = blockIdx.x >> 3;
    const int mb = xcd * 4 + (slot >> 4);
    const int jb = slot & 15;
    const int m0 = mb * 128, j0 = jb * 32;
    unsigned* grp = bar + mb * 16;

    const int wv = tid >> 6, lane = tid & 63, lrow = lane & 15, lk8 = (lane >> 4) * 8;
    const int wm = wv >> 1, wn = wv & 1;

    // B staging geometry (proven layout/swizzle from rounds 3-8)
    const int scolh = (((lane & 7) * 16) ^ (((lane >> 3) & 7) << 4)) >> 1;
    unsigned woffE[4], woffD[4];
    int ldsQ[4];
    #pragma unroll
    for (int q = 0; q < 4; ++q) {
        int r = q * 32 + wv * 8 + (lane >> 3);
        unsigned grow = ((r >> 4) & 3) * H_SZ + j0 + (r >> 6) * 16 + (r & 15);
        woffE[q] = grow * 768u + scolh;
        woffD[q] = grow * 512u + scolh;
        ldsQ[q]  = (q * 256 + wv * 64) * 8;
    }

    // A register-fragment offsets (row = m0+wm*64+mf*16+lrow, k-off = (lane>>4)*8)
    unsigned aoffX[4], aoffH[4];
    #pragma unroll
    for (int mf = 0; mf < 4; ++mf) {
        unsigned row = (unsigned)(m0 + wm * 64 + mf * 16 + lrow);
        aoffX[mf] = row * (unsigned)I_SZ + (unsigned)lk8;
        aoffH[mf] = row * (unsigned)H_SZ + (unsigned)lk8;
    }

    float ebj[4], dbj[4], bdj[4];
    #pragma unroll
    for (int nf = 0; nf < 4; ++nf) {
        int col = nf * H_SZ + j0 + wn * 16 + lrow;
        ebj[nf] = eb[col]; dbj[nf] = db[col]; bdj[nf] = bd[col];
    }

    float creg[4][4];

    auto wait_group = [&](unsigned target) {
        MEMFENCE;
        if (tid == 0) {
            while (__hip_atomic_load(grp, __ATOMIC_RELAXED, __HIP_MEMORY_SCOPE_AGENT) < target)
                __builtin_amdgcn_s_sleep(1);
        }
        __builtin_amdgcn_s_barrier();
        MEMFENCE;
    };

    auto run_step = [&](auto NITERc, auto NXc, bool first, bool sig, unsigned wtarget,
                        const _Float16* xs, const _Float16* hin,
                        const _Float16* wb, const unsigned* woff,
                        const float* bj, _Float16* hout) {
        constexpr int NITER = decltype(NITERc)::value;
        constexpr int NX    = decltype(NXc)::value;

        half8 ar[2][4][2];
        f32x4 acc[4][4];
        #pragma unroll
        for (int mf = 0; mf < 4; ++mf)
            #pragma unroll
            for (int nf = 0; nf < 4; ++nf) {
                f32x4 z = {0.f, 0.f, 0.f, 0.f};
                acc[mf][nf] = z;
            }

        auto loadA = [&](int it2) {
            #pragma unroll
            for (int mf = 0; mf < 4; ++mf)
                #pragma unroll
                for (int kc = 0; kc < 2; ++kc)
                    ar[it2 & 1][mf][kc] = (it2 < NX)
                        ? *(const half8*)(xs + aoffX[mf] + it2 * 64 + kc * 32)
                        : *(const half8*)(hin + aoffH[mf] + (it2 - NX) * 64 + kc * 32);
        };
        auto stageB = [&](int it2) {
            #pragma unroll
            for (int q = 0; q < 4; ++q)
                GLDS(wb + woff[q] + it2 * 64, &Bs[it2 & 3][ldsQ[q]]);
        };

        // ---- prologue (overlaps previous step's h-store drain) ----
        if (NX == 0) {
            stageB(0); stageB(1);
            asm volatile("s_waitcnt vmcnt(8)" ::: "memory");   // drains older sc-stores
            __builtin_amdgcn_s_barrier(); MEMFENCE;
            if (sig && tid == 0)
                __hip_atomic_fetch_add(grp, 1u, __ATOMIC_RELAXED, __HIP_MEMORY_SCOPE_AGENT);
            wait_group(wtarget);
            loadA(0);   // h, after wait
        } else {
            loadA(0); stageB(0); stageB(1);   // x + W, no dependency
            if (sig) {
                asm volatile("s_waitcnt vmcnt(16)" ::: "memory");  // drains older sc-stores
                __builtin_amdgcn_s_barrier(); MEMFENCE;
                if (tid == 0)
                    __hip_atomic_fetch_add(grp, 1u, __ATOMIC_RELAXED, __HIP_MEMORY_SCOPE_AGENT);
            }
        }

        // ---- K-loop: A 1-ahead (regs), B 2-ahead (LDS), 1 barrier/iter ----
        #pragma unroll
        for (int it = 0; it < NITER; ++it) {
            if (NX > 0 && NITER > NX && it == NX - 1) wait_group(wtarget);  // before first h load
            if (it + 1 < NITER) loadA(it + 1);   // A issued BEFORE B (FIFO: B floats 2 deep)
            if (it + 2 < NITER) stageB(it + 2);
            if (NX == 0 && it == 0)   { asm volatile("s_waitcnt vmcnt(12)" ::: "memory"); }
            else if (it + 2 < NITER)  { asm volatile("s_waitcnt vmcnt(16)" ::: "memory"); }
            else if (it + 1 < NITER)  { asm volatile("s_waitcnt vmcnt(12)" ::: "memory"); }
            else                      { asm volatile("s_waitcnt vmcnt(0)"  ::: "memory"); }
            __builtin_amdgcn_s_barrier(); MEMFENCE;
            #pragma unroll
            for (int kc = 0; kc < 2; ++kc) {
                const int sc = (((kc * 32 + lk8) * 2) ^ ((lrow & 7) << 4)) >> 1;
                half8 b[4];
                #pragma unroll
                for (int nf = 0; nf < 4; ++nf)
                    b[nf] = *(const half8*)&Bs[it & 3][(wn * 64 + nf * 16 + lrow) * 64 + sc];
                #pragma unroll
                for (int mf = 0; mf < 4; ++mf)
                    #pragma unroll
                    for (int nf = 0; nf < 4; ++nf)
                        acc[mf][nf] = __builtin_amdgcn_mfma_f32_16x16x32_f16(
                            ar[it & 1][mf][kc], b[nf], acc[mf][nf], 0, 0, 0);
            }
            MEMFENCE;
        }

        // ---- epilogue: activations + cell update; repack via hsm (=Bs[2]) ----
        // Safe: last compute reads Bs[3] (NITER-1 = 3 mod 4 for 4/8/12); Bs[2] is
        // next overwritten only by body(0)'s stageB(2), after the prologue barrier.
        _Float16* hsm = &Bs[2][0];
        const int lc = wn * 16 + lrow;
        #pragma unroll
        for (int mf = 0; mf < 4; ++mf)
            #pragma unroll
            for (int r = 0; r < 4; ++r) {
                int lr = wm * 64 + mf * 16 + (lane >> 4) * 4 + r;
                float gi = acc[mf][0][r] + bj[0];
                float gf = acc[mf][1][r] + bj[1];
                float gg = acc[mf][2][r] + bj[2];
                float go = acc[mf][3][r] + bj[3];
                float cold = first ? 0.0f : creg[mf][r];
                float cn = sigm(gf) * cold + sigm(gi) * tanh_fast(gg);
                creg[mf][r] = cn;
                hsm[lr * PAD_H + lc] = (_Float16)(sigm(go) * tanh_fast(cn));
            }
        __syncthreads();
        {
            int rr = tid >> 3, k = tid & 7;   // 8 lanes/row: full 64B lines per instr
            #pragma unroll
            for (int q = 0; q < 4; ++q) {
                int r = rr + q * 32;
                unsigned long long v = *(const unsigned long long*)&hsm[r * PAD_H + k * 4];
                unsigned long long* dst =
                    (unsigned long long*)(hout + (size_t)(m0 + r) * H_SZ + j0) + k;
                __hip_atomic_store(dst, v, __ATOMIC_RELAXED, __HIP_MEMORY_SCOPE_AGENT);
            }
        }
        // store drain + arrive happen in the NEXT step's prologue (overlapped)
    };

    // ===== encoder step 0 (x only) =====
    run_step(IC<4>{}, IC<4>{}, true, false, 0u,
             xT, henc, Wenc, woffE, ebj, henc);

    // ===== encoder steps 1..49 =====
    for (int s = 1; s < S_SZ; ++s) {
        run_step(IC<12>{}, IC<4>{}, false, true, (unsigned)s * 16u,
                 xT + (size_t)s * B_SZ * I_SZ,
                 henc + (size_t)(s - 1) * BH, Wenc, woffE, ebj,
                 (s == S_SZ - 1) ? hseq : henc + (size_t)s * BH);
    }

    // ===== decoder steps 0..19 (fold: feedback absorbed into Wd/bd) =====
    for (int t = 0; t < T_SZ; ++t) {
        run_step(IC<8>{}, IC<0>{}, false, true, (unsigned)(S_SZ + t) * 16u,
                 henc, hseq + (size_t)t * BH,
                 t ? Wd : dWhh_h, woffD, t ? bdj : dbj,
                 hseq + (size_t)(t + 1) * BH);
    }
}

// ---------------- batched final FC over all decoder h's ----------------
__global__ __launch_bounds__(256) void k_fc(
    const _Float16* __restrict__ hseq1,  // [T][B][512]
    const _Float16* __restrict__ W,      // fcW fp16 [256][512]
    const float* __restrict__ bias,      // [256]
    float* __restrict__ out)
{
    __shared__ _Float16 Asm[128][PAD];
    __shared__ _Float16 Bsm[128][PAD];

    const int tid = threadIdx.x;
    const int m0 = blockIdx.x * 128;
    const int t  = blockIdx.y;
    const int n0 = blockIdx.z * 128;
    const int wv = tid >> 6, lane = tid & 63, lrow = lane & 15, lk = (lane >> 4) * 8;
    const int wm = wv >> 1, wn = wv & 1;

    f32x4 acc[4][4] = {};

    const int srow = tid >> 3, skc = (tid & 7) * 8;
    const _Float16* A = hseq1 + (size_t)t * BH;

    for (int k0 = 0; k0 < H_SZ; k0 += 64) {
        __syncthreads();
        #pragma unroll
        for (int q = 0; q < 4; ++q) {
            int r = srow + q * 32;
            *(half8*)&Asm[r][skc] = *(const half8*)(A + (size_t)(m0 + r) * H_SZ + k0 + skc);
        }
        #pragma unroll
        for (int q = 0; q < 4; ++q) {
            int rr = srow + q * 32;
            *(half8*)&Bsm[rr][skc] = *(const half8*)(W + (size_t)(n0 + rr) * H_SZ + k0 + skc);
        }
        __syncthreads();
        #pragma unroll
        for (int kc = 0; kc < 64; kc += 32) {
            half8 a[4], b[4];
            #pragma unroll
            for (int mf = 0; mf < 4; ++mf) a[mf] = *(const half8*)&Asm[wm * 64 + mf * 16 + lrow][kc + lk];
            #pragma unroll
            for (int nf = 0; nf < 4; ++nf) b[nf] = *(const half8*)&Bsm[wn * 64 + nf * 16 + lrow][kc + lk];
            #pragma unroll
            for (int mf = 0; mf < 4; ++mf)
                #pragma unroll
                for (int nf = 0; nf < 4; ++nf)
                    acc[mf][nf] = __builtin_amdgcn_mfma_f32_16x16x32_f16(a[mf], b[nf], acc[mf][nf], 0, 0, 0);
        }
    }

    #pragma unroll
    for (int mf = 0; mf < 4; ++mf)
        #pragma unroll
        for (int nf = 0; nf < 4; ++nf) {
            int o = n0 + wn * 64 + nf * 16 + lrow;
            float bv = bias[o];
            #pragma unroll
            for (int r = 0; r < 4; ++r) {
                int m = m0 + wm * 64 + mf * 16 + (lane >> 4) * 4 + r;
                out[(size_t)m * (T_SZ * O_SZ) + (size_t)t * O_SZ + o] = acc[mf][nf][r] + bv;
            }
        }
}

extern "C" void kernel_launch(void* const* d_in, const int* in_sizes, int n_in,
                              void* d_out, int out_size, void* d_ws, size_t ws_size,
                              hipStream_t stream) {
    (void)in_sizes; (void)n_in; (void)out_size; (void)ws_size;

    const float* x    = (const float*)d_in[0];
    const float* eWih = (const float*)d_in[1];
    const float* eWhh = (const float*)d_in[2];
    const float* ebih = (const float*)d_in[3];
    const float* ebhh = (const float*)d_in[4];
    const float* dWih = (const float*)d_in[5];
    const float* dWhh = (const float*)d_in[6];
    const float* dbih = (const float*)d_in[7];
    const float* dbhh = (const float*)d_in[8];
    const float* fcW  = (const float*)d_in[9];
    const float* fcb  = (const float*)d_in[10];
    float* out = (float*)d_out;
    char* ws = (char*)d_ws;

    size_t off = 0;
    auto alloc = [&](size_t bytes) -> void* {
        void* p = ws + off;
        off += (bytes + 255) & ~(size_t)255;
        return p;
    };
    _Float16* xT     = (_Float16*)alloc((size_t)S_SZ * B_SZ * I_SZ * 2);
    _Float16* Wenc   = (_Float16*)alloc((size_t)G4H * (I_SZ + H_SZ) * 2);
    _Float16* dWhh_h = (_Float16*)alloc((size_t)G4H * H_SZ * 2);
    _Float16* Wd     = (_Float16*)alloc((size_t)G4H * H_SZ * 2);
    _Float16* fcW_h  = (_Float16*)alloc((size_t)O_SZ * H_SZ * 2);
    float*    eb     = (float*)alloc(G4H * 4);
    float*    db     = (float*)alloc(G4H * 4);
    float*    bd     = (float*)alloc(G4H * 4);
    _Float16* henc   = (_Float16*)alloc((size_t)(S_SZ - 1) * BH * 2);   // 49 slabs
    _Float16* hseq   = (_Float16*)alloc((size_t)(T_SZ + 1) * BH * 2);   // 21 slabs
    unsigned* bar    = (unsigned*)alloc(32 * 16 * 4);

    const int nWhh = G4H * H_SZ;
    const int nFc  = O_SZ * H_SZ;
    const size_t nX = (size_t)B_SZ * S_SZ * I_SZ;

    k_zeroN<<<2, 256, 0, stream>>>(bar, 32 * 16);
    k_cvt_x<<<(int)(nX / 8 / 256), 256, 0, stream>>>(x, xT);
    k_wenc<<<(G4H * 768) / 256, 256, 0, stream>>>(eWih, eWhh, Wenc);
    k_cvt<<<(nWhh + 255) / 256, 256, 0, stream>>>(dWhh, dWhh_h, nWhh);
    k_cvt<<<(nFc + 255) / 256, 256, 0, stream>>>(fcW, fcW_h, nFc);
    k_bias_combine<<<8, 256, 0, stream>>>(ebih, ebhh, eb, G4H);
    k_bias_combine<<<8, 256, 0, stream>>>(dbih, dbhh, db, G4H);
    k_wd<<<256, 256, 0, stream>>>(dWhh, dWih, fcW, Wd);
    k_bd<<<8, 256, 0, stream>>>(dWih, fcb, db, bd);

    k_lstm_all<<<NB, 256, 0, stream>>>(xT, Wenc, dWhh_h, Wd, eb, db, bd,
                                       henc, hseq, bar);

    k_fc<<<dim3(B_SZ / 128, T_SZ, O_SZ / 128), 256, 0, stream>>>(
        hseq + BH, fcW_h, fcb, out);
}

// Round 10
// 1754.759 us; speedup vs baseline: 1.3023x; 1.3023x over previous
//
#include <hip/hip_runtime.h>

#define I_SZ 256
#define H_SZ 512
#define O_SZ 256
#define B_SZ 4096
#define S_SZ 50
#define T_SZ 20
#define G4H  2048
#define BH   ((size_t)B_SZ * H_SZ)
#define NB   512                 // persistent grid: 2 blocks/CU x 256 CUs

#define PAD 72    // k_fc only
#define PAD_H 36  // epilogue h repack stride (halves)

typedef _Float16 half8 __attribute__((ext_vector_type(8)));
typedef float f32x4 __attribute__((ext_vector_type(4)));

template<int N> struct IC { static constexpr int value = N; };

__device__ __forceinline__ float sigm(float x) {
    return 1.0f / (1.0f + __expf(-x));
}
__device__ __forceinline__ float tanh_fast(float x) {
    float e = __expf(2.0f * x);
    return 1.0f - 2.0f / (e + 1.0f);
}

// async global->LDS, 16B/lane, linear LDS dest, cached (L1+L2)
#define GLDS(gp, lp) __builtin_amdgcn_global_load_lds(                      \
    (const __attribute__((address_space(1))) void*)(gp),                    \
    (__attribute__((address_space(3))) void*)(lp), 16, 0, 0)

#define MEMFENCE asm volatile("" ::: "memory")

// ---------------- one-time prep kernels ----------------
__global__ void k_zeroN(unsigned* p, int n) {
    int i = blockIdx.x * blockDim.x + threadIdx.x;
    if (i < n) p[i] = 0u;
}

__global__ void k_cvt(const float* __restrict__ src, _Float16* __restrict__ dst, int n) {
    int i = blockIdx.x * blockDim.x + threadIdx.x;
    if (i < n) dst[i] = (_Float16)src[i];
}

__global__ void k_bias_combine(const float* __restrict__ a, const float* __restrict__ b,
                               float* __restrict__ dst, int n) {
    int i = blockIdx.x * blockDim.x + threadIdx.x;
    if (i < n) dst[i] = a[i] + b[i];
}

// x [B][S][I] fp32 -> xT [S][B][I] fp16
__global__ __launch_bounds__(256) void k_cvt_x(const float* __restrict__ x,
                                               _Float16* __restrict__ xT) {
    size_t idx = ((size_t)blockIdx.x * 256 + threadIdx.x) * 8;
    int i = (int)(idx & 255);
    int s = (int)((idx >> 8) % S_SZ);
    size_t b = idx / (256 * S_SZ);
    float4 v0 = *(const float4*)(x + idx);
    float4 v1 = *(const float4*)(x + idx + 4);
    half8 hv;
    hv[0] = (_Float16)v0.x; hv[1] = (_Float16)v0.y;
    hv[2] = (_Float16)v0.z; hv[3] = (_Float16)v0.w;
    hv[4] = (_Float16)v1.x; hv[5] = (_Float16)v1.y;
    hv[6] = (_Float16)v1.z; hv[7] = (_Float16)v1.w;
    *(half8*)(xT + (((size_t)s * B_SZ + b) * I_SZ + i)) = hv;
}

// Wenc[r][0:256]=eWih[r], [256:768]=eWhh[r]  (fp16)
__global__ void k_wenc(const float* __restrict__ eWih, const float* __restrict__ eWhh,
                       _Float16* __restrict__ Wenc) {
    int idx = blockIdx.x * blockDim.x + threadIdx.x;
    int r = idx / 768, col = idx % 768;
    float v = (col < 256) ? eWih[(size_t)r * 256 + col] : eWhh[(size_t)r * 512 + col - 256];
    Wenc[idx] = (_Float16)v;
}

// Wd[r,k] = dWhh[r,k] + sum_o dWih[r,o] * fcW[o,k]
__global__ __launch_bounds__(256) void k_wd(
    const float* __restrict__ dWhh, const float* __restrict__ dWih,
    const float* __restrict__ fcW, _Float16* __restrict__ Wd)
{
    __shared__ float sA[8][256];
    const int tid = threadIdx.x;
    const int r0 = blockIdx.x * 8;
    {
        int linear = tid * 8;
        int row = linear >> 8, col = linear & 255;
        const float4* p = (const float4*)(dWih + (size_t)(r0 + row) * 256 + col);
        float4 v0 = p[0], v1 = p[1];
        *(float4*)&sA[row][col]     = v0;
        *(float4*)&sA[row][col + 4] = v1;
    }
    __syncthreads();
    float acc[8][2] = {};
    const int k = tid;
    for (int i = 0; i < 256; ++i) {
        float w0 = fcW[(size_t)i * 512 + k];
        float w1 = fcW[(size_t)i * 512 + k + 256];
        #pragma unroll
        for (int rr = 0; rr < 8; ++rr) {
            float a = sA[rr][i];
            acc[rr][0] += a * w0;
            acc[rr][1] += a * w1;
        }
    }
    #pragma unroll
    for (int rr = 0; rr < 8; ++rr) {
        size_t base = (size_t)(r0 + rr) * 512;
        Wd[base + k]       = (_Float16)(dWhh[base + k]       + acc[rr][0]);
        Wd[base + k + 256] = (_Float16)(dWhh[base + k + 256] + acc[rr][1]);
    }
}

// bd[r] = db[r] + sum_o dWih[r,o] * fcb[o]
__global__ __launch_bounds__(256) void k_bd(
    const float* __restrict__ dWih, const float* __restrict__ fcb,
    const float* __restrict__ db, float* __restrict__ bd)
{
    __shared__ float sf[256];
    const int tid = threadIdx.x;
    sf[tid] = fcb[tid];
    __syncthreads();
    int r = blockIdx.x * 256 + tid;
    float acc = db[r];
    const float* row = dWih + (size_t)r * 256;
    for (int o = 0; o < 256; o += 4) {
        float4 v = *(const float4*)(row + o);
        acc += v.x * sf[o] + v.y * sf[o + 1] + v.z * sf[o + 2] + v.w * sf[o + 3];
    }
    bd[r] = acc;
}

// ---------------- persistent whole-recurrence kernel ----------------
// 4x1 wave split: wave wv owns rows wv*32..+31 (A loaded per-lane to regs,
// zero duplication), all 128 gate-cols (B from LDS, shared). B staged via
// global_load_lds into a 4-deep ring, 2-ahead, counted vmcnt, ONE barrier/iter.
// Unique h slab per step; sc write-through h stores + relaxed group counters.
__global__ __launch_bounds__(256, 2) void k_lstm_all(
    const _Float16* __restrict__ xT,     // [S][B][256] fp16
    const _Float16* __restrict__ Wenc,   // [2048][768]
    const _Float16* __restrict__ dWhh_h, // [2048][512]
    const _Float16* __restrict__ Wd,     // [2048][512]
    const float* __restrict__ eb, const float* __restrict__ db,
    const float* __restrict__ bd,
    _Float16* __restrict__ henc,         // [49][B][512] unique slabs
    _Float16* __restrict__ hseq,         // [21][B][512]
    unsigned* __restrict__ bar)          // 32 counters, 16 uints apart
{
    __shared__ _Float16 Bs[4][8192];          // 4 x 16KB B ring
    __shared__ _Float16 hsm[128 * PAD_H];     // dedicated epilogue repack (9 KB)

    const int tid = threadIdx.x;
    const int xcd = blockIdx.x & 7, slot = blockIdx.x >> 3;
    const int mb = xcd * 4 + (slot >> 4);
    const int jb = slot & 15;
    const int m0 = mb * 128, j0 = jb * 32;
    unsigned* grp = bar + mb * 16;

    const int wv = tid >> 6, lane = tid & 63, lrow = lane & 15, lk8 = (lane >> 4) * 8;

    // B staging geometry (proven layout/swizzle, rounds 3-8)
    const int scolh = (((lane & 7) * 16) ^ (((lane >> 3) & 7) << 4)) >> 1;
    unsigned woffE[4], woffD[4];
    int ldsQ[4];
    #pragma unroll
    for (int q = 0; q < 4; ++q) {
        int r = q * 32 + wv * 8 + (lane >> 3);
        unsigned grow = ((r >> 4) & 3) * H_SZ + j0 + (r >> 6) * 16 + (r & 15);
        woffE[q] = grow * 768u + scolh;
        woffD[q] = grow * 512u + scolh;
        ldsQ[q]  = (q * 256 + wv * 64) * 8;
    }

    // A register-fragment offsets: wave wv owns rows wv*32 + mf*16 + lrow
    unsigned aoffX[2], aoffH[2];
    #pragma unroll
    for (int mf = 0; mf < 2; ++mf) {
        unsigned row = (unsigned)(m0 + wv * 32 + mf * 16 + lrow);
        aoffX[mf] = row * (unsigned)I_SZ + (unsigned)lk8;
        aoffH[mf] = row * (unsigned)H_SZ + (unsigned)lk8;
    }

    // biases for this lane's 8 nf-blocks (gate = nf&3, jseg = nf>>2)
    float ebj[8], dbj[8], bdj[8];
    #pragma unroll
    for (int nf = 0; nf < 8; ++nf) {
        int col = (nf & 3) * H_SZ + j0 + (nf >> 2) * 16 + lrow;
        ebj[nf] = eb[col]; dbj[nf] = db[col]; bdj[nf] = bd[col];
    }

    float creg[2][2][4];   // [mf][jseg][r]

    auto wait_group = [&](unsigned target) {
        MEMFENCE;
        if (tid == 0) {
            while (__hip_atomic_load(grp, __ATOMIC_RELAXED, __HIP_MEMORY_SCOPE_AGENT) < target)
                __builtin_amdgcn_s_sleep(1);
        }
        __builtin_amdgcn_s_barrier();
        MEMFENCE;
    };

    auto run_step = [&](auto NITERc, auto NXc, bool first, bool sig, unsigned wtarget,
                        const _Float16* xs, const _Float16* hin,
                        const _Float16* wb, const unsigned (&woff)[4],
                        const float (&bj)[8], _Float16* hout) {
        constexpr int NITER = decltype(NITERc)::value;
        constexpr int NX    = decltype(NXc)::value;

        half8 ar[2][2][2];   // [slot][mf][kc]
        f32x4 acc[2][8];
        #pragma unroll
        for (int mf = 0; mf < 2; ++mf)
            #pragma unroll
            for (int nf = 0; nf < 8; ++nf) {
                f32x4 z = {0.f, 0.f, 0.f, 0.f};
                acc[mf][nf] = z;
            }

        auto loadA = [&](int i2) {
            #pragma unroll
            for (int mf = 0; mf < 2; ++mf)
                #pragma unroll
                for (int kc = 0; kc < 2; ++kc)
                    ar[i2 & 1][mf][kc] = (i2 < NX)
                        ? *(const half8*)(xs + aoffX[mf] + i2 * 64 + kc * 32)
                        : *(const half8*)(hin + aoffH[mf] + (i2 - NX) * 64 + kc * 32);
        };
        auto stageB = [&](int i2) {
            #pragma unroll
            for (int q = 0; q < 4; ++q)
                GLDS(wb + woff[q] + i2 * 64, &Bs[i2 & 3][ldsQ[q]]);
        };

        // ---- prologue ----
        stageB(0);
        if (NITER > 1) stageB(1);
        if (NX == 0) wait_group(wtarget);   // decoder: W loads fly during the wait
        loadA(0);

        // ---- K-loop: A 1-ahead (regs), B 2-ahead (LDS ring), 1 barrier/iter ----
        #pragma unroll
        for (int it = 0; it < NITER; ++it) {
            if (NX > 0 && NITER > NX && it + 1 == NX) wait_group(wtarget);
            if (it + 1 < NITER) loadA(it + 1);
            if (it + 2 < NITER) stageB(it + 2);
            if (it + 2 < NITER)      { asm volatile("s_waitcnt vmcnt(16)" ::: "memory"); }
            else if (it + 1 < NITER) { asm volatile("s_waitcnt vmcnt(8)"  ::: "memory"); }
            else                     { asm volatile("s_waitcnt vmcnt(0)"  ::: "memory"); }
            __builtin_amdgcn_s_barrier(); MEMFENCE;
            #pragma unroll
            for (int kc = 0; kc < 2; ++kc) {
                const int sc = (((kc * 32 + lk8) * 2) ^ ((lrow & 7) << 4)) >> 1;
                half8 b[8];
                #pragma unroll
                for (int nf = 0; nf < 8; ++nf)
                    b[nf] = *(const half8*)&Bs[it & 3][(nf * 16 + lrow) * 64 + sc];
                #pragma unroll
                for (int mf = 0; mf < 2; ++mf)
                    #pragma unroll
                    for (int nf = 0; nf < 8; ++nf)
                        acc[mf][nf] = __builtin_amdgcn_mfma_f32_16x16x32_f16(
                            ar[it & 1][mf][kc], b[nf], acc[mf][nf], 0, 0, 0);
            }
            MEMFENCE;
        }

        // ---- epilogue: activations + cell update; repack via dedicated hsm ----
        __syncthreads();   // all waves done with compute before hsm reuse
        #pragma unroll
        for (int mf = 0; mf < 2; ++mf)
            #pragma unroll
            for (int js = 0; js < 2; ++js)
                #pragma unroll
                for (int r = 0; r < 4; ++r) {
                    int lr = wv * 32 + mf * 16 + (lane >> 4) * 4 + r;
                    float gi = acc[mf][js * 4 + 0][r] + bj[js * 4 + 0];
                    float gf = acc[mf][js * 4 + 1][r] + bj[js * 4 + 1];
                    float gg = acc[mf][js * 4 + 2][r] + bj[js * 4 + 2];
                    float go = acc[mf][js * 4 + 3][r] + bj[js * 4 + 3];
                    float cold = first ? 0.0f : creg[mf][js][r];
                    float cn = sigm(gf) * cold + sigm(gi) * tanh_fast(gg);
                    creg[mf][js][r] = cn;
                    hsm[lr * PAD_H + js * 16 + lrow] = (_Float16)(sigm(go) * tanh_fast(cn));
                }
        __syncthreads();
        {
            int rr = tid >> 3, k = tid & 7;   // 8 lanes/row: full 64B lines per instr
            #pragma unroll
            for (int q = 0; q < 4; ++q) {
                int r = rr + q * 32;
                unsigned long long v = *(const unsigned long long*)&hsm[r * PAD_H + k * 4];
                unsigned long long* dst =
                    (unsigned long long*)(hout + (size_t)(m0 + r) * H_SZ + j0) + k;
                __hip_atomic_store(dst, v, __ATOMIC_RELAXED, __HIP_MEMORY_SCOPE_AGENT);
            }
        }
        if (sig) {
            __syncthreads();   // drains the sc-stores (vmcnt 0) before signaling
            if (tid == 0)
                __hip_atomic_fetch_add(grp, 1u, __ATOMIC_RELAXED, __HIP_MEMORY_SCOPE_AGENT);
        }
    };

    // ===== encoder step 0 (x only) =====
    run_step(IC<4>{}, IC<4>{}, true, true, 0u,
             xT, henc, Wenc, woffE, ebj, henc);

    // ===== encoder steps 1..49 =====
    for (int s = 1; s < S_SZ; ++s) {
        run_step(IC<12>{}, IC<4>{}, false, true, (unsigned)s * 16u,
                 xT + (size_t)s * B_SZ * I_SZ,
                 henc + (size_t)(s - 1) * BH, Wenc, woffE, ebj,
                 (s == S_SZ - 1) ? hseq : henc + (size_t)s * BH);
    }

    // ===== decoder steps 0..19 (fold: feedback absorbed into Wd/bd) =====
    for (int t = 0; t < T_SZ; ++t) {
        if (t == 0)
            run_step(IC<8>{}, IC<0>{}, false, true, (unsigned)(S_SZ + t) * 16u,
                     henc, hseq + (size_t)t * BH, dWhh_h, woffD, dbj,
                     hseq + (size_t)(t + 1) * BH);
        else
            run_step(IC<8>{}, IC<0>{}, false, t != T_SZ - 1, (unsigned)(S_SZ + t) * 16u,
                     henc, hseq + (size_t)t * BH, Wd, woffD, bdj,
                     hseq + (size_t)(t + 1) * BH);
    }
}

// ---------------- batched final FC over all decoder h's ----------------
__global__ __launch_bounds__(256) void k_fc(
    const _Float16* __restrict__ hseq1,  // [T][B][512]
    const _Float16* __restrict__ W,      // fcW fp16 [256][512]
    const float* __restrict__ bias,      // [256]
    float* __restrict__ out)
{
    __shared__ _Float16 Asm[128][PAD];
    __shared__ _Float16 Bsm[128][PAD];

    const int tid = threadIdx.x;
    const int m0 = blockIdx.x * 128;
    const int t  = blockIdx.y;
    const int n0 = blockIdx.z * 128;
    const int wv = tid >> 6, lane = tid & 63, lrow = lane & 15, lk = (lane >> 4) * 8;
    const int wm = wv >> 1, wn = wv & 1;

    f32x4 acc[4][4] = {};

    const int srow = tid >> 3, skc = (tid & 7) * 8;
    const _Float16* A = hseq1 + (size_t)t * BH;

    for (int k0 = 0; k0 < H_SZ; k0 += 64) {
        __syncthreads();
        #pragma unroll
        for (int q = 0; q < 4; ++q) {
            int r = srow + q * 32;
            *(half8*)&Asm[r][skc] = *(const half8*)(A + (size_t)(m0 + r) * H_SZ + k0 + skc);
        }
        #pragma unroll
        for (int q = 0; q < 4; ++q) {
            int rr = srow + q * 32;
            *(half8*)&Bsm[rr][skc] = *(const half8*)(W + (size_t)(n0 + rr) * H_SZ + k0 + skc);
        }
        __syncthreads();
        #pragma unroll
        for (int kc = 0; kc < 64; kc += 32) {
            half8 a[4], b[4];
            #pragma unroll
            for (int mf = 0; mf < 4; ++mf) a[mf] = *(const half8*)&Asm[wm * 64 + mf * 16 + lrow][kc + lk];
            #pragma unroll
            for (int nf = 0; nf < 4; ++nf) b[nf] = *(const half8*)&Bsm[wn * 64 + nf * 16 + lrow][kc + lk];
            #pragma unroll
            for (int mf = 0; mf < 4; ++mf)
                #pragma unroll
                for (int nf = 0; nf < 4; ++nf)
                    acc[mf][nf] = __builtin_amdgcn_mfma_f32_16x16x32_f16(a[mf], b[nf], acc[mf][nf], 0, 0, 0);
        }
    }

    #pragma unroll
    for (int mf = 0; mf < 4; ++mf)
        #pragma unroll
        for (int nf = 0; nf < 4; ++nf) {
            int o = n0 + wn * 64 + nf * 16 + lrow;
            float bv = bias[o];
            #pragma unroll
            for (int r = 0; r < 4; ++r) {
                int m = m0 + wm * 64 + mf * 16 + (lane >> 4) * 4 + r;
                out[(size_t)m * (T_SZ * O_SZ) + (size_t)t * O_SZ + o] = acc[mf][nf][r] + bv;
            }
        }
}

extern "C" void kernel_launch(void* const* d_in, const int* in_sizes, int n_in,
                              void* d_out, int out_size, void* d_ws, size_t ws_size,
                              hipStream_t stream) {
    (void)in_sizes; (void)n_in; (void)out_size; (void)ws_size;

    const float* x    = (const float*)d_in[0];
    const float* eWih = (const float*)d_in[1];
    const float* eWhh = (const float*)d_in[2];
    const float* ebih = (const float*)d_in[3];
    const float* ebhh = (const float*)d_in[4];
    const float* dWih = (const float*)d_in[5];
    const float* dWhh = (const float*)d_in[6];
    const float* dbih = (const float*)d_in[7];
    const float* dbhh = (const float*)d_in[8];
    const float* fcW  = (const float*)d_in[9];
    const float* fcb  = (const float*)d_in[10];
    float* out = (float*)d_out;
    char* ws = (char*)d_ws;

    size_t off = 0;
    auto alloc = [&](size_t bytes) -> void* {
        void* p = ws + off;
        off += (bytes + 255) & ~(size_t)255;
        return p;
    };
    _Float16* xT     = (_Float16*)alloc((size_t)S_SZ * B_SZ * I_SZ * 2);
    _Float16* Wenc   = (_Float16*)alloc((size_t)G4H * (I_SZ + H_SZ) * 2);
    _Float16* dWhh_h = (_Float16*)alloc((size_t)G4H * H_SZ * 2);
    _Float16* Wd     = (_Float16*)alloc((size_t)G4H * H_SZ * 2);
    _Float16* fcW_h  = (_Float16*)alloc((size_t)O_SZ * H_SZ * 2);
    float*    eb     = (float*)alloc(G4H * 4);
    float*    db     = (float*)alloc(G4H * 4);
    float*    bd     = (float*)alloc(G4H * 4);
    _Float16* henc   = (_Float16*)alloc((size_t)(S_SZ - 1) * BH * 2);   // 49 slabs
    _Float16* hseq   = (_Float16*)alloc((size_t)(T_SZ + 1) * BH * 2);   // 21 slabs
    unsigned* bar    = (unsigned*)alloc(32 * 16 * 4);

    const int nWhh = G4H * H_SZ;
    const int nFc  = O_SZ * H_SZ;
    const size_t nX = (size_t)B_SZ * S_SZ * I_SZ;

    k_zeroN<<<2, 256, 0, stream>>>(bar, 32 * 16);
    k_cvt_x<<<(int)(nX / 8 / 256), 256, 0, stream>>>(x, xT);
    k_wenc<<<(G4H * 768) / 256, 256, 0, stream>>>(eWih, eWhh, Wenc);
    k_cvt<<<(nWhh + 255) / 256, 256, 0, stream>>>(dWhh, dWhh_h, nWhh);
    k_cvt<<<(nFc + 255) / 256, 256, 0, stream>>>(fcW, fcW_h, nFc);
    k_bias_combine<<<8, 256, 0, stream>>>(ebih, ebhh, eb, G4H);
    k_bias_combine<<<8, 256, 0, stream>>>(dbih, dbhh, db, G4H);
    k_wd<<<256, 256, 0, stream>>>(dWhh, dWih, fcW, Wd);
    k_bd<<<8, 256, 0, stream>>>(dWih, fcb, db, bd);

    k_lstm_all<<<NB, 256, 0, stream>>>(xT, Wenc, dWhh_h, Wd, eb, db, bd,
                                       henc, hseq, bar);

    k_fc<<<dim3(B_SZ / 128, T_SZ, O_SZ / 128), 256, 0, stream>>>(
        hseq + BH, fcW_h, fcb, out);
}

// Round 11
// 1269.631 us; speedup vs baseline: 1.7999x; 1.3821x over previous
//
#include <hip/hip_runtime.h>

#define I_SZ 256
#define H_SZ 512
#define O_SZ 256
#define B_SZ 4096
#define S_SZ 50
#define T_SZ 20
#define G4H  2048
#define BH   ((size_t)B_SZ * H_SZ)
#define NB   512                 // persistent grid: 2 blocks/CU x 256 CUs

#define PAD 72    // k_fc only
#define PAD_H 36  // epilogue h repack stride (halves)

typedef _Float16 half8 __attribute__((ext_vector_type(8)));
typedef float f32x4 __attribute__((ext_vector_type(4)));

__device__ __forceinline__ float sigm(float x) {
    return 1.0f / (1.0f + __expf(-x));
}
__device__ __forceinline__ float tanh_fast(float x) {
    float e = __expf(2.0f * x);
    return 1.0f - 2.0f / (e + 1.0f);
}

// async global->LDS, 16B/lane, linear LDS dest, cached (L1+L2)
#define GLDS(gp, lp) __builtin_amdgcn_global_load_lds(                      \
    (const __attribute__((address_space(1))) void*)(gp),                    \
    (__attribute__((address_space(3))) void*)(lp), 16, 0, 0)

#define MEMFENCE asm volatile("" ::: "memory")

// ---------------- one-time prep kernels ----------------
__global__ void k_zeroN(unsigned* p, int n) {
    int i = blockIdx.x * blockDim.x + threadIdx.x;
    if (i < n) p[i] = 0u;
}

__global__ void k_cvt(const float* __restrict__ src, _Float16* __restrict__ dst, int n) {
    int i = blockIdx.x * blockDim.x + threadIdx.x;
    if (i < n) dst[i] = (_Float16)src[i];
}

__global__ void k_bias_combine(const float* __restrict__ a, const float* __restrict__ b,
                               float* __restrict__ dst, int n) {
    int i = blockIdx.x * blockDim.x + threadIdx.x;
    if (i < n) dst[i] = a[i] + b[i];
}

// x [B][S][I] fp32 -> xT [S][B][I] fp16
__global__ __launch_bounds__(256) void k_cvt_x(const float* __restrict__ x,
                                               _Float16* __restrict__ xT) {
    size_t idx = ((size_t)blockIdx.x * 256 + threadIdx.x) * 8;
    int i = (int)(idx & 255);
    int s = (int)((idx >> 8) % S_SZ);
    size_t b = idx / (256 * S_SZ);
    float4 v0 = *(const float4*)(x + idx);
    float4 v1 = *(const float4*)(x + idx + 4);
    half8 hv;
    hv[0] = (_Float16)v0.x; hv[1] = (_Float16)v0.y;
    hv[2] = (_Float16)v0.z; hv[3] = (_Float16)v0.w;
    hv[4] = (_Float16)v1.x; hv[5] = (_Float16)v1.y;
    hv[6] = (_Float16)v1.z; hv[7] = (_Float16)v1.w;
    *(half8*)(xT + (((size_t)s * B_SZ + b) * I_SZ + i)) = hv;
}

// Wenc[r][0:256]=eWih[r], [256:768]=eWhh[r]  (fp16)
__global__ void k_wenc(const float* __restrict__ eWih, const float* __restrict__ eWhh,
                       _Float16* __restrict__ Wenc) {
    int idx = blockIdx.x * blockDim.x + threadIdx.x;
    int r = idx / 768, col = idx % 768;
    float v = (col < 256) ? eWih[(size_t)r * 256 + col] : eWhh[(size_t)r * 512 + col - 256];
    Wenc[idx] = (_Float16)v;
}

// Wd[r,k] = dWhh[r,k] + sum_o dWih[r,o] * fcW[o,k]
__global__ __launch_bounds__(256) void k_wd(
    const float* __restrict__ dWhh, const float* __restrict__ dWih,
    const float* __restrict__ fcW, _Float16* __restrict__ Wd)
{
    __shared__ float sA[8][256];
    const int tid = threadIdx.x;
    const int r0 = blockIdx.x * 8;
    {
        int linear = tid * 8;
        int row = linear >> 8, col = linear & 255;
        const float4* p = (const float4*)(dWih + (size_t)(r0 + row) * 256 + col);
        float4 v0 = p[0], v1 = p[1];
        *(float4*)&sA[row][col]     = v0;
        *(float4*)&sA[row][col + 4] = v1;
    }
    __syncthreads();
    float acc[8][2] = {};
    const int k = tid;
    for (int i = 0; i < 256; ++i) {
        float w0 = fcW[(size_t)i * 512 + k];
        float w1 = fcW[(size_t)i * 512 + k + 256];
        #pragma unroll
        for (int rr = 0; rr < 8; ++rr) {
            float a = sA[rr][i];
            acc[rr][0] += a * w0;
            acc[rr][1] += a * w1;
        }
    }
    #pragma unroll
    for (int rr = 0; rr < 8; ++rr) {
        size_t base = (size_t)(r0 + rr) * 512;
        Wd[base + k]       = (_Float16)(dWhh[base + k]       + acc[rr][0]);
        Wd[base + k + 256] = (_Float16)(dWhh[base + k + 256] + acc[rr][1]);
    }
}

// bd[r] = db[r] + sum_o dWih[r,o] * fcb[o]
__global__ __launch_bounds__(256) void k_bd(
    const float* __restrict__ dWih, const float* __restrict__ fcb,
    const float* __restrict__ db, float* __restrict__ bd)
{
    __shared__ float sf[256];
    const int tid = threadIdx.x;
    sf[tid] = fcb[tid];
    __syncthreads();
    int r = blockIdx.x * 256 + tid;
    float acc = db[r];
    const float* row = dWih + (size_t)r * 256;
    for (int o = 0; o < 256; o += 4) {
        float4 v = *(const float4*)(row + o);
        acc += v.x * sf[o] + v.y * sf[o + 1] + v.z * sf[o + 2] + v.w * sf[o + 3];
    }
    bd[r] = acc;
}

// ---------------- persistent whole-recurrence kernel ----------------
// Round-8 structure (GLDS staging, 2-buf, counted vmcnt, unique h slabs,
// sc write-through h stores, relaxed counters) with ONE change: 2-D XCD
// placement (8 mb x 8 jb per XCD) so each XCD's W slice (1.5 MB enc) stays
// L2-resident instead of being evicted by streaming h/x every step.
__global__ __launch_bounds__(256, 2) void k_lstm_all(
    const _Float16* __restrict__ xT,     // [S][B][256] fp16
    const _Float16* __restrict__ Wenc,   // [2048][768]
    const _Float16* __restrict__ dWhh_h, // [2048][512]
    const _Float16* __restrict__ Wd,     // [2048][512]
    const float* __restrict__ eb, const float* __restrict__ db,
    const float* __restrict__ bd,
    _Float16* __restrict__ henc,         // [49][B][512] unique slabs
    _Float16* __restrict__ hseq,         // [21][B][512]
    unsigned* __restrict__ bar)          // 32 counters, 16 uints apart
{
    __shared__ _Float16 lds[2][2][128 * 64];   // 64 KB

    const int tid = threadIdx.x;
    // 2-D placement: XCD x hosts mb-tile (x>>1, 8 mb) x jb-tile (x&1, 8 jb).
    // W per XCD = 8 jb x 192 KB = 1.5 MB (L2-resident); h crosses XCDs via LLC.
    const int xcd = blockIdx.x & 7, slot = blockIdx.x >> 3;
    const int mb = (xcd >> 1) * 8 + (slot >> 3);
    const int jb = (xcd & 1) * 8 + (slot & 7);
    const int m0 = mb * 128, j0 = jb * 32;
    unsigned* grp = bar + mb * 16;

    const int wv = tid >> 6, lane = tid & 63, lrow = lane & 15, lk8 = (lane >> 4) * 8;
    const int wm = wv >> 1, wn = wv & 1;

    // ---- staging geometry: precomputed per-q pointers ----
    const int colb  = (lane & 7) * 16;
    const int scolh = (colb ^ (((lane >> 3) & 7) << 4)) >> 1;
    const _Float16* wEncQ[4]; const _Float16* wD0Q[4]; const _Float16* wDQ[4];
    const _Float16* xQ[4];
    unsigned aOffQ[4];
    int ldsQ[4];
    #pragma unroll
    for (int q = 0; q < 4; ++q) {
        int r = q * 32 + wv * 8 + (lane >> 3);
        int grow = ((r >> 4) & 3) * H_SZ + j0 + (r >> 6) * 16 + (r & 15);
        wEncQ[q] = Wenc   + (size_t)grow * 768 + scolh;
        wD0Q[q]  = dWhh_h + (size_t)grow * 512 + scolh;
        wDQ[q]   = Wd     + (size_t)grow * 512 + scolh;
        xQ[q]    = xT + (size_t)(m0 + r) * I_SZ + scolh;
        aOffQ[q] = (unsigned)((m0 + r) * H_SZ) + scolh;
        ldsQ[q]  = (q * 256 + wv * 64) * 8;
    }

    float ebj[4], dbj[4], bdj[4];
    #pragma unroll
    for (int nf = 0; nf < 4; ++nf) {
        int col = nf * H_SZ + j0 + wn * 16 + lrow;
        ebj[nf] = eb[col]; dbj[nf] = db[col]; bdj[nf] = bd[col];
    }

    float creg[4][4];

    auto wait_group = [&](unsigned target) {
        MEMFENCE;
        if (tid == 0) {
            while (__hip_atomic_load(grp, __ATOMIC_RELAXED, __HIP_MEMORY_SCOPE_AGENT) < target)
                __builtin_amdgcn_s_sleep(1);
        }
        __builtin_amdgcn_s_barrier();
        MEMFENCE;
    };
    auto arrive = [&]() {
        __syncthreads();   // drains h sc-stores (vmcnt 0) before signaling
        if (tid == 0)
            __hip_atomic_fetch_add(grp, 1u, __ATOMIC_RELAXED, __HIP_MEMORY_SCOPE_AGENT);
    };

    auto compute = [&](int buf, f32x4 (&acc)[4][4]) {
        #pragma unroll
        for (int kc = 0; kc < 2; ++kc) {
            const int sc = (((kc * 32 + lk8) * 2) ^ ((lrow & 7) << 4)) >> 1;
            half8 a[4], b[4];
            #pragma unroll
            for (int mf = 0; mf < 4; ++mf)
                a[mf] = *(const half8*)&lds[buf][0][(wm * 64 + mf * 16 + lrow) * 64 + sc];
            #pragma unroll
            for (int nf = 0; nf < 4; ++nf)
                b[nf] = *(const half8*)&lds[buf][1][(wn * 64 + nf * 16 + lrow) * 64 + sc];
            #pragma unroll
            for (int mf = 0; mf < 4; ++mf)
                #pragma unroll
                for (int nf = 0; nf < 4; ++nf)
                    acc[mf][nf] = __builtin_amdgcn_mfma_f32_16x16x32_f16(a[mf], b[nf], acc[mf][nf], 0, 0, 0);
        }
    };

    auto epilogue = [&](f32x4 (&acc)[4][4], const float (&bj)[4], _Float16* hout, bool first) {
        _Float16* hsm = &lds[0][0][0];
        const int lc = wn * 16 + lrow;
        #pragma unroll
        for (int mf = 0; mf < 4; ++mf)
            #pragma unroll
            for (int r = 0; r < 4; ++r) {
                int lr = wm * 64 + mf * 16 + (lane >> 4) * 4 + r;
                float gi = acc[mf][0][r] + bj[0];
                float gf = acc[mf][1][r] + bj[1];
                float gg = acc[mf][2][r] + bj[2];
                float go = acc[mf][3][r] + bj[3];
                float cold = first ? 0.0f : creg[mf][r];
                float cn = sigm(gf) * cold + sigm(gi) * tanh_fast(gg);
                creg[mf][r] = cn;
                hsm[lr * PAD_H + lc] = (_Float16)(sigm(go) * tanh_fast(cn));
            }
        __syncthreads();
        int rr = tid >> 3, k = tid & 7;
        #pragma unroll
        for (int q = 0; q < 4; ++q) {
            int r = rr + q * 32;
            unsigned long long v = *(const unsigned long long*)&hsm[r * PAD_H + k * 4];
            unsigned long long* dst =
                (unsigned long long*)(hout + (size_t)(m0 + r) * H_SZ + j0) + k;
            __hip_atomic_store(dst, v, __ATOMIC_RELAXED, __HIP_MEMORY_SCOPE_AGENT);
        }
    };

    // ================= phase A: encoder step 0 (x only, 4 tiles) =================
    {
        f32x4 acc[4][4] = {};
        #pragma unroll
        for (int q = 0; q < 4; ++q) { GLDS(xQ[q], &lds[0][0][ldsQ[q]]); GLDS(wEncQ[q], &lds[0][1][ldsQ[q]]); }
        #pragma unroll
        for (int it = 0; it < 4; ++it) {
            if (it < 3) {
                #pragma unroll
                for (int q = 0; q < 4; ++q) {
                    GLDS(xQ[q] + (it + 1) * 64, &lds[(it + 1) & 1][0][ldsQ[q]]);
                    GLDS(wEncQ[q] + (it + 1) * 64, &lds[(it + 1) & 1][1][ldsQ[q]]);
                }
                asm volatile("s_waitcnt vmcnt(8)" ::: "memory");
            } else {
                asm volatile("s_waitcnt vmcnt(0)" ::: "memory");
            }
            __builtin_amdgcn_s_barrier(); MEMFENCE;
            compute(it & 1, acc);
            MEMFENCE; __builtin_amdgcn_s_barrier(); MEMFENCE;
        }
        epilogue(acc, ebj, henc, true);
        arrive();
    }

    // ================= phase B: encoder steps 1..49 (12 tiles) =================
    for (int s = 1; s < S_SZ; ++s) {
        const size_t xoff = (size_t)s * B_SZ * I_SZ;
        const _Float16* hin = henc + (size_t)(s - 1) * BH;
        _Float16* hout = (s == S_SZ - 1) ? hseq : henc + (size_t)s * BH;
        f32x4 acc[4][4] = {};
        #pragma unroll
        for (int q = 0; q < 4; ++q) { GLDS(xQ[q] + xoff, &lds[0][0][ldsQ[q]]); GLDS(wEncQ[q], &lds[0][1][ldsQ[q]]); }
        #pragma unroll
        for (int it = 0; it < 12; ++it) {
            if (it < 11) {
                if (it == 3) wait_group((unsigned)s * 16u);
                #pragma unroll
                for (int q = 0; q < 4; ++q) {
                    if (it + 1 < 4) GLDS(xQ[q] + xoff + (it + 1) * 64, &lds[(it + 1) & 1][0][ldsQ[q]]);
                    else            GLDS(hin + aOffQ[q] + (it - 3) * 64, &lds[(it + 1) & 1][0][ldsQ[q]]);
                    GLDS(wEncQ[q] + (it + 1) * 64, &lds[(it + 1) & 1][1][ldsQ[q]]);
                }
                asm volatile("s_waitcnt vmcnt(8)" ::: "memory");
            } else {
                asm volatile("s_waitcnt vmcnt(0)" ::: "memory");
            }
            __builtin_amdgcn_s_barrier(); MEMFENCE;
            compute(it & 1, acc);
            MEMFENCE; __builtin_amdgcn_s_barrier(); MEMFENCE;
        }
        epilogue(acc, ebj, hout, false);
        arrive();
    }

    // ================= phase C: decoder steps 0..19 (8 tiles) =================
    for (int t = 0; t < T_SZ; ++t) {
        const _Float16* hin = hseq + (size_t)t * BH;
        _Float16* hout = hseq + (size_t)(t + 1) * BH;
        const _Float16* wq[4];
        float bj[4];
        #pragma unroll
        for (int q = 0; q < 4; ++q) wq[q] = t ? wDQ[q] : wD0Q[q];
        #pragma unroll
        for (int nf = 0; nf < 4; ++nf) bj[nf] = t ? bdj[nf] : dbj[nf];

        wait_group((unsigned)(S_SZ + t) * 16u);
        f32x4 acc[4][4] = {};
        #pragma unroll
        for (int q = 0; q < 4; ++q) { GLDS(hin + aOffQ[q], &lds[0][0][ldsQ[q]]); GLDS(wq[q], &lds[0][1][ldsQ[q]]); }
        #pragma unroll
        for (int it = 0; it < 8; ++it) {
            if (it < 7) {
                #pragma unroll
                for (int q = 0; q < 4; ++q) {
                    GLDS(hin + aOffQ[q] + (it + 1) * 64, &lds[(it + 1) & 1][0][ldsQ[q]]);
                    GLDS(wq[q] + (it + 1) * 64, &lds[(it + 1) & 1][1][ldsQ[q]]);
                }
                asm volatile("s_waitcnt vmcnt(8)" ::: "memory");
            } else {
                asm volatile("s_waitcnt vmcnt(0)" ::: "memory");
            }
            __builtin_amdgcn_s_barrier(); MEMFENCE;
            compute(it & 1, acc);
            MEMFENCE; __builtin_amdgcn_s_barrier(); MEMFENCE;
        }
        epilogue(acc, bj, hout, false);
        if (t != T_SZ - 1) arrive();
    }
}

// ---------------- batched final FC over all decoder h's ----------------
__global__ __launch_bounds__(256) void k_fc(
    const _Float16* __restrict__ hseq1,  // [T][B][512]
    const _Float16* __restrict__ W,      // fcW fp16 [256][512]
    const float* __restrict__ bias,      // [256]
    float* __restrict__ out)
{
    __shared__ _Float16 Asm[128][PAD];
    __shared__ _Float16 Bsm[128][PAD];

    const int tid = threadIdx.x;
    const int m0 = blockIdx.x * 128;
    const int t  = blockIdx.y;
    const int n0 = blockIdx.z * 128;
    const int wv = tid >> 6, lane = tid & 63, lrow = lane & 15, lk = (lane >> 4) * 8;
    const int wm = wv >> 1, wn = wv & 1;

    f32x4 acc[4][4] = {};

    const int srow = tid >> 3, skc = (tid & 7) * 8;
    const _Float16* A = hseq1 + (size_t)t * BH;

    for (int k0 = 0; k0 < H_SZ; k0 += 64) {
        __syncthreads();
        #pragma unroll
        for (int q = 0; q < 4; ++q) {
            int r = srow + q * 32;
            *(half8*)&Asm[r][skc] = *(const half8*)(A + (size_t)(m0 + r) * H_SZ + k0 + skc);
        }
        #pragma unroll
        for (int q = 0; q < 4; ++q) {
            int rr = srow + q * 32;
            *(half8*)&Bsm[rr][skc] = *(const half8*)(W + (size_t)(n0 + rr) * H_SZ + k0 + skc);
        }
        __syncthreads();
        #pragma unroll
        for (int kc = 0; kc < 64; kc += 32) {
            half8 a[4], b[4];
            #pragma unroll
            for (int mf = 0; mf < 4; ++mf) a[mf] = *(const half8*)&Asm[wm * 64 + mf * 16 + lrow][kc + lk];
            #pragma unroll
            for (int nf = 0; nf < 4; ++nf) b[nf] = *(const half8*)&Bsm[wn * 64 + nf * 16 + lrow][kc + lk];
            #pragma unroll
            for (int mf = 0; mf < 4; ++mf)
                #pragma unroll
                for (int nf = 0; nf < 4; ++nf)
                    acc[mf][nf] = __builtin_amdgcn_mfma_f32_16x16x32_f16(a[mf], b[nf], acc[mf][nf], 0, 0, 0);
        }
    }

    #pragma unroll
    for (int mf = 0; mf < 4; ++mf)
        #pragma unroll
        for (int nf = 0; nf < 4; ++nf) {
            int o = n0 + wn * 64 + nf * 16 + lrow;
            float bv = bias[o];
            #pragma unroll
            for (int r = 0; r < 4; ++r) {
                int m = m0 + wm * 64 + mf * 16 + (lane >> 4) * 4 + r;
                out[(size_t)m * (T_SZ * O_SZ) + (size_t)t * O_SZ + o] = acc[mf][nf][r] + bv;
            }
        }
}

extern "C" void kernel_launch(void* const* d_in, const int* in_sizes, int n_in,
                              void* d_out, int out_size, void* d_ws, size_t ws_size,
                              hipStream_t stream) {
    (void)in_sizes; (void)n_in; (void)out_size; (void)ws_size;

    const float* x    = (const float*)d_in[0];
    const float* eWih = (const float*)d_in[1];
    const float* eWhh = (const float*)d_in[2];
    const float* ebih = (const float*)d_in[3];
    const float* ebhh = (const float*)d_in[4];
    const float* dWih = (const float*)d_in[5];
    const float* dWhh = (const float*)d_in[6];
    const float* dbih = (const float*)d_in[7];
    const float* dbhh = (const float*)d_in[8];
    const float* fcW  = (const float*)d_in[9];
    const float* fcb  = (const float*)d_in[10];
    float* out = (float*)d_out;
    char* ws = (char*)d_ws;

    size_t off = 0;
    auto alloc = [&](size_t bytes) -> void* {
        void* p = ws + off;
        off += (bytes + 255) & ~(size_t)255;
        return p;
    };
    _Float16* xT     = (_Float16*)alloc((size_t)S_SZ * B_SZ * I_SZ * 2);
    _Float16* Wenc   = (_Float16*)alloc((size_t)G4H * (I_SZ + H_SZ) * 2);
    _Float16* dWhh_h = (_Float16*)alloc((size_t)G4H * H_SZ * 2);
    _Float16* Wd     = (_Float16*)alloc((size_t)G4H * H_SZ * 2);
    _Float16* fcW_h  = (_Float16*)alloc((size_t)O_SZ * H_SZ * 2);
    float*    eb     = (float*)alloc(G4H * 4);
    float*    db     = (float*)alloc(G4H * 4);
    float*    bd     = (float*)alloc(G4H * 4);
    _Float16* henc   = (_Float16*)alloc((size_t)(S_SZ - 1) * BH * 2);   // 49 slabs
    _Float16* hseq   = (_Float16*)alloc((size_t)(T_SZ + 1) * BH * 2);   // 21 slabs
    unsigned* bar    = (unsigned*)alloc(32 * 16 * 4);

    const int nWhh = G4H * H_SZ;
    const int nFc  = O_SZ * H_SZ;
    const size_t nX = (size_t)B_SZ * S_SZ * I_SZ;

    k_zeroN<<<2, 256, 0, stream>>>(bar, 32 * 16);
    k_cvt_x<<<(int)(nX / 8 / 256), 256, 0, stream>>>(x, xT);
    k_wenc<<<(G4H * 768) / 256, 256, 0, stream>>>(eWih, eWhh, Wenc);
    k_cvt<<<(nWhh + 255) / 256, 256, 0, stream>>>(dWhh, dWhh_h, nWhh);
    k_cvt<<<(nFc + 255) / 256, 256, 0, stream>>>(fcW, fcW_h, nFc);
    k_bias_combine<<<8, 256, 0, stream>>>(ebih, ebhh, eb, G4H);
    k_bias_combine<<<8, 256, 0, stream>>>(dbih, dbhh, db, G4H);
    k_wd<<<256, 256, 0, stream>>>(dWhh, dWih, fcW, Wd);
    k_bd<<<8, 256, 0, stream>>>(dWih, fcb, db, bd);

    k_lstm_all<<<NB, 256, 0, stream>>>(xT, Wenc, dWhh_h, Wd, eb, db, bd,
                                       henc, hseq, bar);

    k_fc<<<dim3(B_SZ / 128, T_SZ, O_SZ / 128), 256, 0, stream>>>(
        hseq + BH, fcW_h, fcb, out);
}